// Round 19
// baseline (136.459 us; speedup 1.0000x reference)
//
#include <hip/hip_runtime.h>

#define NN 8000
#define NE 64000
#define INF 16
#define HH 128
#define MM 16
#define EDF 4
#define OUTF 4
#define NL 2
#define BN_EPS 1e-5f
#define BPR 2080          // Bp rows per layer: 2048 qn + 16 b2 + 16 rootW
#define CAP 48            // per-node edge bucket capacity
#define QS 2052           // sQ node stride in halfs

typedef __attribute__((ext_vector_type(8))) short short8;
typedef __attribute__((ext_vector_type(4))) float f32x4;

static __device__ __forceinline__ unsigned short f2bf(float f) {
  unsigned u = __builtin_bit_cast(unsigned, f);
  u = (u + 0x7fffu + ((u >> 16) & 1u)) >> 16;
  return (unsigned short)u;
}
static __device__ __forceinline__ float bf2f(unsigned short s) {
  unsigned u = ((unsigned)s) << 16;
  return __builtin_bit_cast(float, u);
}
static __device__ __forceinline__ int qperm(int k) {
  return ((k >> 3) & 3) | ((k & 7) << 2) | (k & 0x60);
}

// edge bucket-scatter (0..499) + Bp build (500..759) + agg zero (760..884)
__global__ __launch_bounds__(128) void front_k(
    const int* __restrict__ ei, const float* __restrict__ ea,
    const float* __restrict__ W2, const float* __restrict__ b2,
    const float* __restrict__ rW,
    float* __restrict__ deg, int* __restrict__ cnt,
    unsigned short* __restrict__ Bp, float* __restrict__ agg,
    float* __restrict__ ea_s, int* __restrict__ dst_s) {
  int blk = blockIdx.x;
  int t = threadIdx.x;

  if (blk < 500) {
    int e = blk * 128 + t;
    int src = ei[e], dst = ei[NE + e];
    atomicAdd(&deg[dst], 1.0f);
    int slot = atomicAdd(&cnt[src], 1);
    int p = src * CAP + slot;
    *(float4*)&ea_s[(size_t)p * 4] = *(const float4*)&ea[(size_t)e * 4];
    dst_s[p] = dst;
  } else if (blk < 756) {
    int r = blk - 500;            // 0..255
    int l = r >> 7, k = r & 127;
    const float* w2row = W2 + (size_t)l * (HH * HH * MM) + (size_t)k * 2048;
    float4 v0 = *(const float4*)&w2row[t * 16 + 0];
    float4 v1 = *(const float4*)&w2row[t * 16 + 4];
    float4 v2 = *(const float4*)&w2row[t * 16 + 8];
    float4 v3 = *(const float4*)&w2row[t * 16 + 12];
    unsigned short* bpr = Bp + ((size_t)l * BPR + (size_t)k * 16) * HH + t;
#pragma unroll
    for (int j = 0; j < 4; ++j) bpr[(0 + j) * HH] = f2bf((&v0.x)[j]);
#pragma unroll
    for (int j = 0; j < 4; ++j) bpr[(4 + j) * HH] = f2bf((&v1.x)[j]);
#pragma unroll
    for (int j = 0; j < 4; ++j) bpr[(8 + j) * HH] = f2bf((&v2.x)[j]);
#pragma unroll
    for (int j = 0; j < 4; ++j) bpr[(12 + j) * HH] = f2bf((&v3.x)[j]);
  } else if (blk < 760) {
    int isroot = (blk >= 758);
    int l = (blk - 756) & 1;
    const float* src = isroot ? (rW + (size_t)l * HH * MM) : (b2 + (size_t)l * 2048);
    float4 v0 = *(const float4*)&src[t * 16 + 0];
    float4 v1 = *(const float4*)&src[t * 16 + 4];
    float4 v2 = *(const float4*)&src[t * 16 + 8];
    float4 v3 = *(const float4*)&src[t * 16 + 12];
    unsigned short* bpr = Bp + ((size_t)l * BPR + 2048 + isroot * 16) * HH + t;
#pragma unroll
    for (int j = 0; j < 4; ++j) bpr[(0 + j) * HH] = f2bf((&v0.x)[j]);
#pragma unroll
    for (int j = 0; j < 4; ++j) bpr[(4 + j) * HH] = f2bf((&v1.x)[j]);
#pragma unroll
    for (int j = 0; j < 4; ++j) bpr[(8 + j) * HH] = f2bf((&v2.x)[j]);
#pragma unroll
    for (int j = 0; j < 4; ++j) bpr[(12 + j) * HH] = f2bf((&v3.x)[j]);
  } else if (blk < 885) {
    int i = (blk - 760) * 256 + t;
    uint4 z = make_uint4(0, 0, 0, 0);
    ((uint4*)agg)[i] = z;
    ((uint4*)agg)[i + 128] = z;
  }
}

// Fused layer: 16 src nodes/block, 1024 threads, __launch_bounds__(1024,8)
// -> VGPR<=64, 2 blocks/CU, 8 waves/SIMD. LDS ~74.7KB (sIW/sX aliased into sQ).
// Layer 0: A = bf16(x@inW+inb) inline (writes hb). Layer 1: A = bf16(BN_relu(hpre)).
// GEMM: wave w -> ctiles [w*8, w*8+8); wave14 +B2 (LDS), wave15 +Xroot (global).
// Contract: wave w -> node w; P = relu1 @ Qn_tile[node]; atomics into agg.
__global__ __launch_bounds__(1024, 8) void fused_layer_k(
    const float* __restrict__ x, const float* __restrict__ inW,
    const float* __restrict__ inb, unsigned short* __restrict__ hb,
    const float* __restrict__ hpre,
    const float* __restrict__ bnsums, const float* __restrict__ gamma,
    const float* __restrict__ beta, int bn_mode,
    const unsigned short* __restrict__ Bp,
    const float* __restrict__ ea_s, const int* __restrict__ dst_s,
    const int* __restrict__ cnt, const float* __restrict__ W1,
    const float* __restrict__ b1, float* __restrict__ agg,
    float* __restrict__ Xroot) {
  __shared__ unsigned short sA[16 * 136];
  __shared__ unsigned short sQ[16 * QS];   // also hosts sIW (8KB) + sX (1KB) pre-GEMM
  __shared__ float sW1[EDF * HH];
  __shared__ float sb1[HH];
  __shared__ float sB2[16][17];
  __shared__ float sscl[HH], sshf[HH];

  float* sIW = (float*)sQ;                 // 2048 f32 = halfs [0,4096)
  float* sX = (float*)(sQ + 4096);         // 256 f32  = halfs [4096,4608)

  int tid = threadIdx.x;
  int n0 = blockIdx.x * 16;
  int wid = tid >> 6, lane = tid & 63;
  int l15 = lane & 15, l4 = lane >> 4;

  for (int i = tid; i < EDF * HH; i += 1024) sW1[i] = W1[i];
  if (tid < HH) sb1[tid] = b1[tid];
  if (bn_mode) {
    if (tid >= 128 && tid < 256) {
      int c = tid - 128;
      float mu = bnsums[c] * (1.0f / NN);
      float var = bnsums[HH + c] * (1.0f / NN) - mu * mu;
      float sc = gamma[c] * rsqrtf(var + BN_EPS);
      sscl[c] = sc;
      sshf[c] = beta[c] - mu * sc;
    }
  } else {
    if (tid >= 256 && tid < 512) sX[tid - 256] = x[(size_t)n0 * INF + (tid - 256)];
    if (tid >= 768 && tid < 896) sscl[tid - 768] = inb[tid - 768];
    for (int i = tid; i < INF * HH; i += 1024) sIW[i] = inW[i];
  }
  __syncthreads();

  // stage A tile (16 nodes x 128 cols, bf16)
  if (bn_mode == 0) {
    if (tid < 512) {
      int nl = tid >> 5;            // 0..15
      int c0 = (tid & 31) * 4;
      ushort4 o;
#pragma unroll
      for (int j = 0; j < 4; ++j) {
        int c = c0 + j;
        float acc = sscl[c];        // inb
#pragma unroll
        for (int i = 0; i < INF; ++i) acc = fmaf(sX[nl * INF + i], sIW[i * HH + c], acc);
        (&o.x)[j] = f2bf(acc);
      }
      *(ushort4*)&sA[nl * 136 + c0] = o;
      *(ushort4*)&hb[(size_t)(n0 + nl) * HH + c0] = o;
    }
  } else if (tid < 256) {
    int node = tid >> 4;            // 0..15
    int c0 = (tid & 15) * 8;
    int ng = n0 + node;
    float4 v0 = *(const float4*)&hpre[(size_t)ng * HH + c0];
    float4 v1 = *(const float4*)&hpre[(size_t)ng * HH + c0 + 4];
    short8 o;
#pragma unroll
    for (int j = 0; j < 4; ++j) {
      o[j] = (short)f2bf(fmaxf(0.f, fmaf((&v0.x)[j], sscl[c0 + j], sshf[c0 + j])));
      o[4 + j] = (short)f2bf(fmaxf(0.f, fmaf((&v1.x)[j], sscl[c0 + 4 + j], sshf[c0 + 4 + j])));
    }
    *(short8*)&sA[node * 136 + c0] = o;
  }
  __syncthreads();

  short8 A0 = *(const short8*)&sA[l15 * 136 + 0 * 32 + l4 * 8];
  short8 A1 = *(const short8*)&sA[l15 * 136 + 1 * 32 + l4 * 8];
  short8 A2 = *(const short8*)&sA[l15 * 136 + 2 * 32 + l4 * 8];
  short8 A3 = *(const short8*)&sA[l15 * 136 + 3 * 32 + l4 * 8];

  // ---- GEMM phase: wave handles ctiles [wid*8, wid*8+8) ----
  int ctb = wid * 8;
  for (int ct = ctb; ct < ctb + 8; ++ct) {
    const unsigned short* p_ = Bp + ((size_t)(ct * 16 + l15)) * HH + l4 * 8;
    short8 b0 = *(const short8*)(p_);
    short8 b1v = *(const short8*)(p_ + 32);
    short8 b2v_ = *(const short8*)(p_ + 64);
    short8 b3 = *(const short8*)(p_ + 96);
    f32x4 pa = {0.f, 0.f, 0.f, 0.f};
    pa = __builtin_amdgcn_mfma_f32_16x16x32_bf16(A0, b0, pa, 0, 0, 0);
    pa = __builtin_amdgcn_mfma_f32_16x16x32_bf16(A1, b1v, pa, 0, 0, 0);
    pa = __builtin_amdgcn_mfma_f32_16x16x32_bf16(A2, b2v_, pa, 0, 0, 0);
    pa = __builtin_amdgcn_mfma_f32_16x16x32_bf16(A3, b3, pa, 0, 0, 0);
    int kq = qperm(ct) * 16 + l15;
    sQ[(l4 * 4 + 0) * QS + kq] = f2bf(pa[0]);
    sQ[(l4 * 4 + 1) * QS + kq] = f2bf(pa[1]);
    sQ[(l4 * 4 + 2) * QS + kq] = f2bf(pa[2]);
    sQ[(l4 * 4 + 3) * QS + kq] = f2bf(pa[3]);
  }

  // extra ctiles: wave 14 -> B2 (rows 2048..2063, LDS); wave 15 -> Xroot (global)
  if (wid >= 14) {
    int base = (wid == 14) ? 2048 : 2064;
    const unsigned short* p = Bp + ((size_t)(base + l15)) * HH + l4 * 8;
    short8 c0 = *(const short8*)(p);
    short8 c1 = *(const short8*)(p + 32);
    short8 c2 = *(const short8*)(p + 64);
    short8 c3 = *(const short8*)(p + 96);
    f32x4 pa = {0.f, 0.f, 0.f, 0.f};
    pa = __builtin_amdgcn_mfma_f32_16x16x32_bf16(A0, c0, pa, 0, 0, 0);
    pa = __builtin_amdgcn_mfma_f32_16x16x32_bf16(A1, c1, pa, 0, 0, 0);
    pa = __builtin_amdgcn_mfma_f32_16x16x32_bf16(A2, c2, pa, 0, 0, 0);
    pa = __builtin_amdgcn_mfma_f32_16x16x32_bf16(A3, c3, pa, 0, 0, 0);
    if (wid == 14) {
#pragma unroll
      for (int j = 0; j < 4; ++j) sB2[l4 * 4 + j][l15] = pa[j];
    } else {
#pragma unroll
      for (int j = 0; j < 4; ++j)
        Xroot[(size_t)(n0 + l4 * 4 + j) * MM + l15] = pa[j];
    }
  }
  __syncthreads();

  // ---- Contract phase: wave handles node wid ----
  {
    int nl = wid;
    int n = n0 + nl;
    int count = cnt[n];
    if (count == 0) return;

    const unsigned short* sq = &sQ[nl * QS];
    short8 qb0, qb1, qb2, qb3;
#pragma unroll
    for (int j = 0; j < 8; ++j) {
      qb0[j] = (short)sq[qperm(0 * 32 + l4 * 8 + j) * 16 + l15];
      qb1[j] = (short)sq[qperm(1 * 32 + l4 * 8 + j) * 16 + l15];
      qb2[j] = (short)sq[qperm(2 * 32 + l4 * 8 + j) * 16 + l15];
      qb3[j] = (short)sq[qperm(3 * 32 + l4 * 8 + j) * 16 + l15];
    }
    float b2v = sB2[nl][l15];

    const float* eab = ea_s + (size_t)n * CAP * 4;
    const int* dsb = dst_s + (size_t)n * CAP;
    for (int t0 = 0; t0 < count; t0 += 16) {
      int rr = t0 + l15;
      bool valid = rr < count;
      float4 eav = valid ? *(const float4*)&eab[(size_t)rr * 4]
                         : make_float4(0.f, 0.f, 0.f, 0.f);
      f32x4 acc = {0.f, 0.f, 0.f, 0.f};
#pragma unroll
      for (int ks = 0; ks < 4; ++ks) {
        short8 a;
#pragma unroll
        for (int j = 0; j < 8; ++j) {
          int k = ks * 32 + l4 * 8 + j;
          float r = fmaf(eav.w, sW1[3 * HH + k],
                     fmaf(eav.z, sW1[2 * HH + k],
                       fmaf(eav.y, sW1[HH + k], fmaf(eav.x, sW1[k], sb1[k]))));
          a[j] = valid ? (short)f2bf(fmaxf(r, 0.f)) : (short)0;
        }
        short8 qb = (ks == 0) ? qb0 : (ks == 1) ? qb1 : (ks == 2) ? qb2 : qb3;
        acc = __builtin_amdgcn_mfma_f32_16x16x32_bf16(a, qb, acc, 0, 0, 0);
      }
#pragma unroll
      for (int j = 0; j < 4; ++j) {
        int r = t0 + l4 * 4 + j;
        if (r < count) {
          atomicAdd(&agg[(size_t)dsb[r] * MM + l15], acc[j] + b2v);
        }
      }
    }
  }
}

// 16 nodes/block: xm = agg/deg + Xroot + cbias ; hp = resid + xm@msgW + msgb
// fused BN partial sums; zeroes its agg slice for next layer.
__global__ __launch_bounds__(256) void node_update_k(
    const unsigned short* __restrict__ hb, const float* __restrict__ hsrc_pre,
    const float* __restrict__ bnsums, const float* __restrict__ gamma,
    const float* __restrict__ beta, int bn_mode,
    float* __restrict__ agg, const float* __restrict__ deg,
    const float* __restrict__ Xroot, const float* __restrict__ cbias,
    const float* __restrict__ msgW, const float* __restrict__ msgb,
    float* __restrict__ hpre, float* __restrict__ sums) {
  __shared__ float smw[MM * HH];
  __shared__ float xm[16][MM];
  __shared__ float scb[MM];
  __shared__ float smb[HH];
  __shared__ float red[256];
  __shared__ float sscl[HH], sshf[HH];
  int tid = threadIdx.x;
  int n0 = blockIdx.x * 16;
  for (int i = tid; i < MM * HH; i += 256) smw[i] = msgW[i];
  if (tid < MM) scb[tid] = cbias[tid];
  if (tid < HH) smb[tid] = msgb[tid];
  if (bn_mode && tid < HH) {
    float mu = bnsums[tid] * (1.0f / NN);
    float var = bnsums[HH + tid] * (1.0f / NN) - mu * mu;
    float sc = gamma[tid] * rsqrtf(var + BN_EPS);
    sscl[tid] = sc;
    sshf[tid] = beta[tid] - mu * sc;
  }
  __syncthreads();

  {
    int ni = tid >> 4, m = tid & 15;
    int n = n0 + ni;
    size_t idx = (size_t)n * MM + m;
    xm[ni][m] = agg[idx] / fmaxf(deg[n], 1.0f) + Xroot[idx] + scb[m];
  }
  __syncthreads();
  agg[(size_t)n0 * MM + tid] = 0.f;

  int t = tid & 127;
  float lsum = 0.f, lss = 0.f;
#pragma unroll
  for (int pass = 0; pass < 8; ++pass) {
    int ni = pass * 2 + (tid >> 7);
    size_t idx = (size_t)(n0 + ni) * HH + t;
    float resid;
    if (bn_mode) {
      resid = fmaxf(0.f, fmaf(hsrc_pre[idx], sscl[t], sshf[t]));
    } else {
      resid = bf2f(hb[idx]);
    }
    float hp = resid + smb[t];
#pragma unroll
    for (int m = 0; m < MM; ++m) hp = fmaf(xm[ni][m], smw[m * HH + t], hp);
    hpre[idx] = hp;
    lsum += hp;
    lss = fmaf(hp, hp, lss);
  }
  red[tid] = lsum;
  __syncthreads();
  if (tid < 128) atomicAdd(&sums[t], red[tid] + red[tid + 128]);
  __syncthreads();
  red[tid] = lss;
  __syncthreads();
  if (tid < 128) atomicAdd(&sums[HH + t], red[tid] + red[tid + 128]);
}

__global__ void out_proj_k(const float* __restrict__ hpre,
                           const float* __restrict__ bnsums,
                           const float* __restrict__ gamma,
                           const float* __restrict__ beta,
                           const float* __restrict__ W, const float* __restrict__ b,
                           float* __restrict__ out) {
  __shared__ float sscl[HH], sshf[HH];
  int tid = threadIdx.x;
  if (tid < HH) {
    float mu = bnsums[tid] * (1.0f / NN);
    float var = bnsums[HH + tid] * (1.0f / NN) - mu * mu;
    float sc = gamma[tid] * rsqrtf(var + BN_EPS);
    sscl[tid] = sc;
    sshf[tid] = beta[tid] - mu * sc;
  }
  __syncthreads();
  int n = blockIdx.x * 4 + (tid >> 6);
  int lane = tid & 63;
  if (n >= NN) return;
  float acc0 = 0.f, acc1 = 0.f, acc2 = 0.f, acc3 = 0.f;
#pragma unroll
  for (int rep = 0; rep < 2; ++rep) {
    int hh = lane + rep * 64;
    float hv = fmaxf(0.f, fmaf(hpre[(size_t)n * HH + hh], sscl[hh], sshf[hh]));
    acc0 = fmaf(hv, W[hh * OUTF + 0], acc0);
    acc1 = fmaf(hv, W[hh * OUTF + 1], acc1);
    acc2 = fmaf(hv, W[hh * OUTF + 2], acc2);
    acc3 = fmaf(hv, W[hh * OUTF + 3], acc3);
  }
#pragma unroll
  for (int s = 32; s > 0; s >>= 1) {
    acc0 += __shfl_down(acc0, s);
    acc1 += __shfl_down(acc1, s);
    acc2 += __shfl_down(acc2, s);
    acc3 += __shfl_down(acc3, s);
  }
  if (lane == 0) {
    out[n * OUTF + 0] = acc0 + b[0];
    out[n * OUTF + 1] = acc1 + b[1];
    out[n * OUTF + 2] = acc2 + b[2];
    out[n * OUTF + 3] = acc3 + b[3];
  }
}

extern "C" void kernel_launch(void* const* d_in, const int* in_sizes, int n_in,
                              void* d_out, int out_size, void* d_ws, size_t ws_size,
                              hipStream_t stream) {
  (void)in_sizes; (void)n_in; (void)out_size; (void)ws_size;
  const float* x    = (const float*)d_in[0];
  const int* ei     = (const int*)d_in[1];
  const float* ea   = (const float*)d_in[2];
  const float* inW  = (const float*)d_in[3];
  const float* inb  = (const float*)d_in[4];
  const float* cW1  = (const float*)d_in[5];
  const float* cb1  = (const float*)d_in[6];
  const float* cW2  = (const float*)d_in[7];
  const float* cb2  = (const float*)d_in[8];
  const float* rW   = (const float*)d_in[9];
  const float* cbias= (const float*)d_in[10];
  const float* gam  = (const float*)d_in[11];
  const float* bet  = (const float*)d_in[12];
  const float* mW   = (const float*)d_in[13];
  const float* mb   = (const float*)d_in[14];
  const float* oW   = (const float*)d_in[15];
  const float* ob   = (const float*)d_in[16];
  float* out = (float*)d_out;

  float* ws = (float*)d_ws;
  size_t off = 0;
  // contiguous zero region: deg, cnt, sums0, sums1 (one small memset)
  float* deg   = ws + off; off += 8192;
  int* cnt     = (int*)(ws + off); off += 8192;
  float* sums0 = ws + off; off += 256;
  float* sums1 = ws + off; off += 256;
  size_t zero_floats = off;
  float* agg   = ws + off; off += (size_t)NN * MM;      // zeroed by front_k
  float* hpre0 = ws + off; off += (size_t)NN * HH;
  float* hpre1 = ws + off; off += (size_t)NN * HH;
  float* Xroot = ws + off; off += (size_t)NN * MM;
  unsigned short* hb = (unsigned short*)(ws + off); off += (size_t)NN * HH / 2;
  unsigned short* Bp = (unsigned short*)(ws + off); off += (size_t)NL * BPR * HH / 2;
  float* ea_s  = ws + off; off += (size_t)NN * CAP * 4;
  int* dst_s   = (int*)(ws + off); off += (size_t)NN * CAP;

  hipMemsetAsync(deg, 0, zero_floats * sizeof(float), stream);
  front_k<<<885, 128, 0, stream>>>(ei, ea, cW2, cb2, rW, deg, cnt, Bp, agg,
                                   ea_s, dst_s);

  // ---- layer 0 (inline in_proj) ----
  fused_layer_k<<<NN / 16, 1024, 0, stream>>>(x, inW, inb, hb, hpre0,
                                              sums0, gam, bet, 0,
                                              Bp, ea_s, dst_s, cnt, cW1, cb1,
                                              agg, Xroot);
  node_update_k<<<NN / 16, 256, 0, stream>>>(hb, hpre0, sums0, gam, bet, 0,
                                             agg, deg, Xroot, cbias, mW, mb,
                                             hpre0, sums0);
  // ---- layer 1 ----
  fused_layer_k<<<NN / 16, 1024, 0, stream>>>(x, inW, inb, hb, hpre0,
                                              sums0, gam, bet, 1,
                                              Bp + (size_t)BPR * HH, ea_s, dst_s,
                                              cnt, cW1 + EDF * HH, cb1 + HH,
                                              agg, Xroot);
  node_update_k<<<NN / 16, 256, 0, stream>>>(hb, hpre0, sums0, gam, bet, 1,
                                             agg, deg, Xroot, cbias + MM,
                                             mW + MM * HH, mb + HH,
                                             hpre1, sums1);
  out_proj_k<<<NN / 4, 256, 0, stream>>>(hpre1, sums1, gam + HH, bet + HH,
                                         oW, ob, out);
}

// Round 20
// 101.828 us; speedup vs baseline: 1.3401x; 1.3401x over previous
//
#include <hip/hip_runtime.h>

#define NN 8000
#define NE 64000
#define INF 16
#define HH 128
#define MM 16
#define EDF 4
#define OUTF 4
#define NL 2
#define BN_EPS 1e-5f
#define BPL (130 * 2048)  // Bp2 halfs per layer: 128 qn-cts + b2-ct + rootW-ct
#define CAP 48            // per-node edge bucket capacity
#define QS 2052           // sQ node stride in halfs

typedef __attribute__((ext_vector_type(8))) short short8;
typedef __attribute__((ext_vector_type(4))) float f32x4;

static __device__ __forceinline__ unsigned short f2bf(float f) {
  unsigned u = __builtin_bit_cast(unsigned, f);
  u = (u + 0x7fffu + ((u >> 16) & 1u)) >> 16;
  return (unsigned short)u;
}
static __device__ __forceinline__ float bf2f(unsigned short s) {
  unsigned u = ((unsigned)s) << 16;
  return __builtin_bit_cast(float, u);
}
static __device__ __forceinline__ int qperm(int k) {
  return ((k >> 3) & 3) | ((k & 7) << 2) | (k & 0x60);
}
// Bp2 position of element (ct-slot, m, h): fragment-linear so a wave's B-frag
// load is contiguous: pos = ct*2048 + (h>>5)*512 + ((h>>3)&3)*128 + m*8 + (h&7)
static __device__ __forceinline__ int bp2pos(int h) {
  return ((h >> 5) << 9) + (((h >> 3) & 3) << 7) + (h & 7);
}

// edge bucket-scatter (0..499) + Bp2 build (500..759) + agg zero (760..884)
__global__ __launch_bounds__(128) void front_k(
    const int* __restrict__ ei, const float* __restrict__ ea,
    const float* __restrict__ W2, const float* __restrict__ b2,
    const float* __restrict__ rW,
    float* __restrict__ deg, int* __restrict__ cnt,
    unsigned short* __restrict__ Bp, float* __restrict__ agg,
    float* __restrict__ ea_s, int* __restrict__ dst_s) {
  int blk = blockIdx.x;
  int t = threadIdx.x;

  if (blk < 500) {
    int e = blk * 128 + t;
    int src = ei[e], dst = ei[NE + e];
    atomicAdd(&deg[dst], 1.0f);
    int slot = atomicAdd(&cnt[src], 1);
    int p = src * CAP + slot;
    *(float4*)&ea_s[(size_t)p * 4] = *(const float4*)&ea[(size_t)e * 4];
    dst_s[p] = dst;
  } else if (blk < 756) {
    int r = blk - 500;            // 0..255
    int l = r >> 7, k = r & 127;
    const float* w2row = W2 + (size_t)l * (HH * HH * MM) + (size_t)k * 2048;
    float4 v0 = *(const float4*)&w2row[t * 16 + 0];
    float4 v1 = *(const float4*)&w2row[t * 16 + 4];
    float4 v2 = *(const float4*)&w2row[t * 16 + 8];
    float4 v3 = *(const float4*)&w2row[t * 16 + 12];
    unsigned short* bp = Bp + (size_t)l * BPL + (size_t)k * 2048 + bp2pos(t);
#pragma unroll
    for (int j = 0; j < 4; ++j) bp[(0 + j) * 8] = f2bf((&v0.x)[j]);
#pragma unroll
    for (int j = 0; j < 4; ++j) bp[(4 + j) * 8] = f2bf((&v1.x)[j]);
#pragma unroll
    for (int j = 0; j < 4; ++j) bp[(8 + j) * 8] = f2bf((&v2.x)[j]);
#pragma unroll
    for (int j = 0; j < 4; ++j) bp[(12 + j) * 8] = f2bf((&v3.x)[j]);
  } else if (blk < 760) {
    int isroot = (blk >= 758);
    int l = (blk - 756) & 1;
    const float* src = isroot ? (rW + (size_t)l * HH * MM) : (b2 + (size_t)l * 2048);
    float4 v0 = *(const float4*)&src[t * 16 + 0];
    float4 v1 = *(const float4*)&src[t * 16 + 4];
    float4 v2 = *(const float4*)&src[t * 16 + 8];
    float4 v3 = *(const float4*)&src[t * 16 + 12];
    unsigned short* bp = Bp + (size_t)l * BPL + (size_t)(128 + isroot) * 2048 + bp2pos(t);
#pragma unroll
    for (int j = 0; j < 4; ++j) bp[(0 + j) * 8] = f2bf((&v0.x)[j]);
#pragma unroll
    for (int j = 0; j < 4; ++j) bp[(4 + j) * 8] = f2bf((&v1.x)[j]);
#pragma unroll
    for (int j = 0; j < 4; ++j) bp[(8 + j) * 8] = f2bf((&v2.x)[j]);
#pragma unroll
    for (int j = 0; j < 4; ++j) bp[(12 + j) * 8] = f2bf((&v3.x)[j]);
  } else if (blk < 885) {
    int i = (blk - 760) * 256 + t;
    uint4 z = make_uint4(0, 0, 0, 0);
    ((uint4*)agg)[i] = z;
    ((uint4*)agg)[i + 128] = z;
  }
}

// Fused layer, 32 src nodes/block, 1024 threads (16 waves, 4/SIMD, 1 block/CU).
// B-frag loads now FULLY COALESCED (Bp2 fragment-linear: 1KB contiguous per load).
// Layer 0: A = bf16(x@inW+inb) inline (writes hb). Layer 1: A = bf16(BN_relu(hpre)).
__global__ __launch_bounds__(1024) void fused_layer_k(
    const float* __restrict__ x, const float* __restrict__ inW,
    const float* __restrict__ inb, unsigned short* __restrict__ hb,
    const float* __restrict__ hpre,
    const float* __restrict__ bnsums, const float* __restrict__ gamma,
    const float* __restrict__ beta, int bn_mode,
    const unsigned short* __restrict__ Bp,
    const float* __restrict__ ea_s, const int* __restrict__ dst_s,
    const int* __restrict__ cnt, const float* __restrict__ W1,
    const float* __restrict__ b1, float* __restrict__ agg,
    float* __restrict__ Xroot) {
  __shared__ unsigned short sA[2 * 16 * 136];
  __shared__ unsigned short sQ[2 * 16 * QS];
  __shared__ float sW1[EDF * HH];
  __shared__ float sb1[HH];
  __shared__ float sB2[32][17];
  __shared__ float sscl[HH], sshf[HH];
  __shared__ float sIW[INF * HH];
  __shared__ float sX[32 * INF];

  int tid = threadIdx.x;
  int n0 = blockIdx.x * 32;
  int wid = tid >> 6, lane = tid & 63;
  int l15 = lane & 15, l4 = lane >> 4;

  for (int i = tid; i < EDF * HH; i += 1024) sW1[i] = W1[i];
  if (tid < HH) sb1[tid] = b1[tid];
  if (bn_mode) {
    if (tid >= 128 && tid < 256) {
      int c = tid - 128;
      float mu = bnsums[c] * (1.0f / NN);
      float var = bnsums[HH + c] * (1.0f / NN) - mu * mu;
      float sc = gamma[c] * rsqrtf(var + BN_EPS);
      sscl[c] = sc;
      sshf[c] = beta[c] - mu * sc;
    }
  } else {
    if (tid >= 256 && tid < 768) sX[tid - 256] = x[(size_t)n0 * INF + (tid - 256)];
    if (tid >= 768 && tid < 896) sscl[tid - 768] = inb[tid - 768];
    for (int i = tid & 1023; i < INF * HH; i += 1024) sIW[i] = inW[i];
  }
  __syncthreads();

  // stage both A tiles
  if (bn_mode == 0) {
    int nl = tid >> 5;
    int c0 = (tid & 31) * 4;
    int g = nl >> 4;
    ushort4 o;
#pragma unroll
    for (int j = 0; j < 4; ++j) {
      int c = c0 + j;
      float acc = sscl[c];  // inb
#pragma unroll
      for (int i = 0; i < INF; ++i) acc = fmaf(sX[nl * INF + i], sIW[i * HH + c], acc);
      (&o.x)[j] = f2bf(acc);
    }
    *(ushort4*)&sA[g * 2176 + (nl & 15) * 136 + c0] = o;
    *(ushort4*)&hb[(size_t)(n0 + nl) * HH + c0] = o;
  } else if (tid < 512) {
    int g = tid >> 8;
    int node = (tid >> 4) & 15;
    int c0 = (tid & 15) * 8;
    int ng = n0 + g * 16 + node;
    float4 v0 = *(const float4*)&hpre[(size_t)ng * HH + c0];
    float4 v1 = *(const float4*)&hpre[(size_t)ng * HH + c0 + 4];
    short8 o;
#pragma unroll
    for (int j = 0; j < 4; ++j) {
      o[j] = (short)f2bf(fmaxf(0.f, fmaf((&v0.x)[j], sscl[c0 + j], sshf[c0 + j])));
      o[4 + j] = (short)f2bf(fmaxf(0.f, fmaf((&v1.x)[j], sscl[c0 + 4 + j], sshf[c0 + 4 + j])));
    }
    *(short8*)&sA[g * 2176 + node * 136 + c0] = o;
  }
  __syncthreads();

  short8 A0 = *(const short8*)&sA[l15 * 136 + 0 * 32 + l4 * 8];
  short8 A1 = *(const short8*)&sA[l15 * 136 + 1 * 32 + l4 * 8];
  short8 A2 = *(const short8*)&sA[l15 * 136 + 2 * 32 + l4 * 8];
  short8 A3 = *(const short8*)&sA[l15 * 136 + 3 * 32 + l4 * 8];
  short8 A4 = *(const short8*)&sA[2176 + l15 * 136 + 0 * 32 + l4 * 8];
  short8 A5 = *(const short8*)&sA[2176 + l15 * 136 + 1 * 32 + l4 * 8];
  short8 A6 = *(const short8*)&sA[2176 + l15 * 136 + 2 * 32 + l4 * 8];
  short8 A7 = *(const short8*)&sA[2176 + l15 * 136 + 3 * 32 + l4 * 8];

  // ---- GEMM phase: ctiles [wid*8, wid*8+8), 3-deep pipelined, coalesced loads ----
  int ctb = wid * 8;

#define LDB4(a_, b_, c_, d_, CT)                                              \
  do {                                                                        \
    const unsigned short* p_ = Bp + (size_t)(CT) * 2048 + lane * 8;           \
    a_ = *(const short8*)(p_);                                                \
    b_ = *(const short8*)(p_ + 512);                                          \
    c_ = *(const short8*)(p_ + 1024);                                         \
    d_ = *(const short8*)(p_ + 1536);                                         \
  } while (0)

#define STEP(a_, b_, c_, d_, CT)                                              \
  do {                                                                        \
    f32x4 pa_ = {0.f, 0.f, 0.f, 0.f};                                         \
    f32x4 qa_ = {0.f, 0.f, 0.f, 0.f};                                         \
    pa_ = __builtin_amdgcn_mfma_f32_16x16x32_bf16(A0, a_, pa_, 0, 0, 0);      \
    pa_ = __builtin_amdgcn_mfma_f32_16x16x32_bf16(A1, b_, pa_, 0, 0, 0);      \
    pa_ = __builtin_amdgcn_mfma_f32_16x16x32_bf16(A2, c_, pa_, 0, 0, 0);      \
    pa_ = __builtin_amdgcn_mfma_f32_16x16x32_bf16(A3, d_, pa_, 0, 0, 0);      \
    qa_ = __builtin_amdgcn_mfma_f32_16x16x32_bf16(A4, a_, qa_, 0, 0, 0);      \
    qa_ = __builtin_amdgcn_mfma_f32_16x16x32_bf16(A5, b_, qa_, 0, 0, 0);      \
    qa_ = __builtin_amdgcn_mfma_f32_16x16x32_bf16(A6, c_, qa_, 0, 0, 0);      \
    qa_ = __builtin_amdgcn_mfma_f32_16x16x32_bf16(A7, d_, qa_, 0, 0, 0);      \
    int kq_ = qperm(CT) * 16 + l15;                                           \
    sQ[(l4 * 4 + 0) * QS + kq_] = f2bf(pa_[0]);                               \
    sQ[(l4 * 4 + 1) * QS + kq_] = f2bf(pa_[1]);                               \
    sQ[(l4 * 4 + 2) * QS + kq_] = f2bf(pa_[2]);                               \
    sQ[(l4 * 4 + 3) * QS + kq_] = f2bf(pa_[3]);                               \
    sQ[16 * QS + (l4 * 4 + 0) * QS + kq_] = f2bf(qa_[0]);                     \
    sQ[16 * QS + (l4 * 4 + 1) * QS + kq_] = f2bf(qa_[1]);                     \
    sQ[16 * QS + (l4 * 4 + 2) * QS + kq_] = f2bf(qa_[2]);                     \
    sQ[16 * QS + (l4 * 4 + 3) * QS + kq_] = f2bf(qa_[3]);                     \
  } while (0)

  {
    short8 u0, u1, u2, u3, v0, v1, v2, v3, w0, w1, w2, w3;
    LDB4(u0, u1, u2, u3, ctb + 0);
    LDB4(v0, v1, v2, v3, ctb + 1);
    LDB4(w0, w1, w2, w3, ctb + 2);
    __builtin_amdgcn_sched_barrier(0);
    __builtin_amdgcn_s_setprio(1);
    STEP(u0, u1, u2, u3, ctb + 0);
    LDB4(u0, u1, u2, u3, ctb + 3);
    __builtin_amdgcn_sched_barrier(0);
    STEP(v0, v1, v2, v3, ctb + 1);
    LDB4(v0, v1, v2, v3, ctb + 4);
    __builtin_amdgcn_sched_barrier(0);
    STEP(w0, w1, w2, w3, ctb + 2);
    LDB4(w0, w1, w2, w3, ctb + 5);
    __builtin_amdgcn_sched_barrier(0);
    STEP(u0, u1, u2, u3, ctb + 3);
    LDB4(u0, u1, u2, u3, ctb + 6);
    __builtin_amdgcn_sched_barrier(0);
    STEP(v0, v1, v2, v3, ctb + 4);
    LDB4(v0, v1, v2, v3, ctb + 7);
    __builtin_amdgcn_sched_barrier(0);
    STEP(w0, w1, w2, w3, ctb + 5);
    STEP(u0, u1, u2, u3, ctb + 6);
    STEP(v0, v1, v2, v3, ctb + 7);
    __builtin_amdgcn_s_setprio(0);
  }
#undef STEP
#undef LDB4

  // extra ctiles: wave 14 -> B2 (ct-slot 128, LDS); wave 15 -> Xroot (ct-slot 129)
  if (wid >= 14) {
    int slot = (wid == 14) ? 128 : 129;
    const unsigned short* p = Bp + (size_t)slot * 2048 + lane * 8;
    short8 c0 = *(const short8*)(p);
    short8 c1 = *(const short8*)(p + 512);
    short8 c2 = *(const short8*)(p + 1024);
    short8 c3 = *(const short8*)(p + 1536);
    f32x4 pa = {0.f, 0.f, 0.f, 0.f};
    f32x4 qa = {0.f, 0.f, 0.f, 0.f};
    pa = __builtin_amdgcn_mfma_f32_16x16x32_bf16(A0, c0, pa, 0, 0, 0);
    pa = __builtin_amdgcn_mfma_f32_16x16x32_bf16(A1, c1, pa, 0, 0, 0);
    pa = __builtin_amdgcn_mfma_f32_16x16x32_bf16(A2, c2, pa, 0, 0, 0);
    pa = __builtin_amdgcn_mfma_f32_16x16x32_bf16(A3, c3, pa, 0, 0, 0);
    qa = __builtin_amdgcn_mfma_f32_16x16x32_bf16(A4, c0, qa, 0, 0, 0);
    qa = __builtin_amdgcn_mfma_f32_16x16x32_bf16(A5, c1, qa, 0, 0, 0);
    qa = __builtin_amdgcn_mfma_f32_16x16x32_bf16(A6, c2, qa, 0, 0, 0);
    qa = __builtin_amdgcn_mfma_f32_16x16x32_bf16(A7, c3, qa, 0, 0, 0);
    if (wid == 14) {
#pragma unroll
      for (int j = 0; j < 4; ++j) {
        sB2[l4 * 4 + j][l15] = pa[j];
        sB2[16 + l4 * 4 + j][l15] = qa[j];
      }
    } else {
#pragma unroll
      for (int j = 0; j < 4; ++j) {
        Xroot[(size_t)(n0 + l4 * 4 + j) * MM + l15] = pa[j];
        Xroot[(size_t)(n0 + 16 + l4 * 4 + j) * MM + l15] = qa[j];
      }
    }
  }
  __syncthreads();

  // ---- Contract phase: wave handles 2 nodes (1 in each group) ----
  for (int gi = 0; gi < 2; ++gi) {
    int nl = gi * 16 + wid;
    int n = n0 + nl;
    int count = cnt[n];
    if (count == 0) continue;

    const unsigned short* sq = &sQ[gi * 16 * QS + (nl & 15) * QS];
    short8 qb0, qb1, qb2, qb3;
#pragma unroll
    for (int j = 0; j < 8; ++j) {
      qb0[j] = (short)sq[qperm(0 * 32 + l4 * 8 + j) * 16 + l15];
      qb1[j] = (short)sq[qperm(1 * 32 + l4 * 8 + j) * 16 + l15];
      qb2[j] = (short)sq[qperm(2 * 32 + l4 * 8 + j) * 16 + l15];
      qb3[j] = (short)sq[qperm(3 * 32 + l4 * 8 + j) * 16 + l15];
    }
    float b2v = sB2[nl][l15];

    const float* eab = ea_s + (size_t)n * CAP * 4;
    const int* dsb = dst_s + (size_t)n * CAP;
    for (int t0 = 0; t0 < count; t0 += 16) {
      int rr = t0 + l15;
      bool valid = rr < count;
      float4 eav = valid ? *(const float4*)&eab[(size_t)rr * 4]
                         : make_float4(0.f, 0.f, 0.f, 0.f);
      f32x4 acc = {0.f, 0.f, 0.f, 0.f};
#pragma unroll
      for (int ks = 0; ks < 4; ++ks) {
        short8 a;
#pragma unroll
        for (int j = 0; j < 8; ++j) {
          int k = ks * 32 + l4 * 8 + j;
          float r = fmaf(eav.w, sW1[3 * HH + k],
                     fmaf(eav.z, sW1[2 * HH + k],
                       fmaf(eav.y, sW1[HH + k], fmaf(eav.x, sW1[k], sb1[k]))));
          a[j] = valid ? (short)f2bf(fmaxf(r, 0.f)) : (short)0;
        }
        short8 qb = (ks == 0) ? qb0 : (ks == 1) ? qb1 : (ks == 2) ? qb2 : qb3;
        acc = __builtin_amdgcn_mfma_f32_16x16x32_bf16(a, qb, acc, 0, 0, 0);
      }
#pragma unroll
      for (int j = 0; j < 4; ++j) {
        int r = t0 + l4 * 4 + j;
        if (r < count) {
          atomicAdd(&agg[(size_t)dsb[r] * MM + l15], acc[j] + b2v);
        }
      }
    }
  }
}

// 16 nodes/block: xm = agg/deg + Xroot + cbias ; hp = resid + xm@msgW + msgb
// fused BN partial sums; zeroes its agg slice for next layer.
__global__ __launch_bounds__(256) void node_update_k(
    const unsigned short* __restrict__ hb, const float* __restrict__ hsrc_pre,
    const float* __restrict__ bnsums, const float* __restrict__ gamma,
    const float* __restrict__ beta, int bn_mode,
    float* __restrict__ agg, const float* __restrict__ deg,
    const float* __restrict__ Xroot, const float* __restrict__ cbias,
    const float* __restrict__ msgW, const float* __restrict__ msgb,
    float* __restrict__ hpre, float* __restrict__ sums) {
  __shared__ float smw[MM * HH];
  __shared__ float xm[16][MM];
  __shared__ float scb[MM];
  __shared__ float smb[HH];
  __shared__ float red[256];
  __shared__ float sscl[HH], sshf[HH];
  int tid = threadIdx.x;
  int n0 = blockIdx.x * 16;
  for (int i = tid; i < MM * HH; i += 256) smw[i] = msgW[i];
  if (tid < MM) scb[tid] = cbias[tid];
  if (tid < HH) smb[tid] = msgb[tid];
  if (bn_mode && tid < HH) {
    float mu = bnsums[tid] * (1.0f / NN);
    float var = bnsums[HH + tid] * (1.0f / NN) - mu * mu;
    float sc = gamma[tid] * rsqrtf(var + BN_EPS);
    sscl[tid] = sc;
    sshf[tid] = beta[tid] - mu * sc;
  }
  __syncthreads();

  {
    int ni = tid >> 4, m = tid & 15;
    int n = n0 + ni;
    size_t idx = (size_t)n * MM + m;
    xm[ni][m] = agg[idx] / fmaxf(deg[n], 1.0f) + Xroot[idx] + scb[m];
  }
  __syncthreads();
  agg[(size_t)n0 * MM + tid] = 0.f;

  int t = tid & 127;
  float lsum = 0.f, lss = 0.f;
#pragma unroll
  for (int pass = 0; pass < 8; ++pass) {
    int ni = pass * 2 + (tid >> 7);
    size_t idx = (size_t)(n0 + ni) * HH + t;
    float resid;
    if (bn_mode) {
      resid = fmaxf(0.f, fmaf(hsrc_pre[idx], sscl[t], sshf[t]));
    } else {
      resid = bf2f(hb[idx]);
    }
    float hp = resid + smb[t];
#pragma unroll
    for (int m = 0; m < MM; ++m) hp = fmaf(xm[ni][m], smw[m * HH + t], hp);
    hpre[idx] = hp;
    lsum += hp;
    lss = fmaf(hp, hp, lss);
  }
  red[tid] = lsum;
  __syncthreads();
  if (tid < 128) atomicAdd(&sums[t], red[tid] + red[tid + 128]);
  __syncthreads();
  red[tid] = lss;
  __syncthreads();
  if (tid < 128) atomicAdd(&sums[HH + t], red[tid] + red[tid + 128]);
}

__global__ void out_proj_k(const float* __restrict__ hpre,
                           const float* __restrict__ bnsums,
                           const float* __restrict__ gamma,
                           const float* __restrict__ beta,
                           const float* __restrict__ W, const float* __restrict__ b,
                           float* __restrict__ out) {
  __shared__ float sscl[HH], sshf[HH];
  int tid = threadIdx.x;
  if (tid < HH) {
    float mu = bnsums[tid] * (1.0f / NN);
    float var = bnsums[HH + tid] * (1.0f / NN) - mu * mu;
    float sc = gamma[tid] * rsqrtf(var + BN_EPS);
    sscl[tid] = sc;
    sshf[tid] = beta[tid] - mu * sc;
  }
  __syncthreads();
  int n = blockIdx.x * 4 + (tid >> 6);
  int lane = tid & 63;
  if (n >= NN) return;
  float acc0 = 0.f, acc1 = 0.f, acc2 = 0.f, acc3 = 0.f;
#pragma unroll
  for (int rep = 0; rep < 2; ++rep) {
    int hh = lane + rep * 64;
    float hv = fmaxf(0.f, fmaf(hpre[(size_t)n * HH + hh], sscl[hh], sshf[hh]));
    acc0 = fmaf(hv, W[hh * OUTF + 0], acc0);
    acc1 = fmaf(hv, W[hh * OUTF + 1], acc1);
    acc2 = fmaf(hv, W[hh * OUTF + 2], acc2);
    acc3 = fmaf(hv, W[hh * OUTF + 3], acc3);
  }
#pragma unroll
  for (int s = 32; s > 0; s >>= 1) {
    acc0 += __shfl_down(acc0, s);
    acc1 += __shfl_down(acc1, s);
    acc2 += __shfl_down(acc2, s);
    acc3 += __shfl_down(acc3, s);
  }
  if (lane == 0) {
    out[n * OUTF + 0] = acc0 + b[0];
    out[n * OUTF + 1] = acc1 + b[1];
    out[n * OUTF + 2] = acc2 + b[2];
    out[n * OUTF + 3] = acc3 + b[3];
  }
}

extern "C" void kernel_launch(void* const* d_in, const int* in_sizes, int n_in,
                              void* d_out, int out_size, void* d_ws, size_t ws_size,
                              hipStream_t stream) {
  (void)in_sizes; (void)n_in; (void)out_size; (void)ws_size;
  const float* x    = (const float*)d_in[0];
  const int* ei     = (const int*)d_in[1];
  const float* ea   = (const float*)d_in[2];
  const float* inW  = (const float*)d_in[3];
  const float* inb  = (const float*)d_in[4];
  const float* cW1  = (const float*)d_in[5];
  const float* cb1  = (const float*)d_in[6];
  const float* cW2  = (const float*)d_in[7];
  const float* cb2  = (const float*)d_in[8];
  const float* rW   = (const float*)d_in[9];
  const float* cbias= (const float*)d_in[10];
  const float* gam  = (const float*)d_in[11];
  const float* bet  = (const float*)d_in[12];
  const float* mW   = (const float*)d_in[13];
  const float* mb   = (const float*)d_in[14];
  const float* oW   = (const float*)d_in[15];
  const float* ob   = (const float*)d_in[16];
  float* out = (float*)d_out;

  float* ws = (float*)d_ws;
  size_t off = 0;
  // contiguous zero region: deg, cnt, sums0, sums1 (one small memset)
  float* deg   = ws + off; off += 8192;
  int* cnt     = (int*)(ws + off); off += 8192;
  float* sums0 = ws + off; off += 256;
  float* sums1 = ws + off; off += 256;
  size_t zero_floats = off;
  float* agg   = ws + off; off += (size_t)NN * MM;      // zeroed by front_k
  float* hpre0 = ws + off; off += (size_t)NN * HH;
  float* hpre1 = ws + off; off += (size_t)NN * HH;
  float* Xroot = ws + off; off += (size_t)NN * MM;
  unsigned short* hb = (unsigned short*)(ws + off); off += (size_t)NN * HH / 2;
  unsigned short* Bp = (unsigned short*)(ws + off); off += (size_t)NL * BPL / 2;
  float* ea_s  = ws + off; off += (size_t)NN * CAP * 4;
  int* dst_s   = (int*)(ws + off); off += (size_t)NN * CAP;

  hipMemsetAsync(deg, 0, zero_floats * sizeof(float), stream);
  front_k<<<885, 128, 0, stream>>>(ei, ea, cW2, cb2, rW, deg, cnt, Bp, agg,
                                   ea_s, dst_s);

  // ---- layer 0 (inline in_proj) ----
  fused_layer_k<<<NN / 32, 1024, 0, stream>>>(x, inW, inb, hb, hpre0,
                                              sums0, gam, bet, 0,
                                              Bp, ea_s, dst_s, cnt, cW1, cb1,
                                              agg, Xroot);
  node_update_k<<<NN / 16, 256, 0, stream>>>(hb, hpre0, sums0, gam, bet, 0,
                                             agg, deg, Xroot, cbias, mW, mb,
                                             hpre0, sums0);
  // ---- layer 1 ----
  fused_layer_k<<<NN / 32, 1024, 0, stream>>>(x, inW, inb, hb, hpre0,
                                              sums0, gam, bet, 1,
                                              Bp + (size_t)BPL, ea_s, dst_s,
                                              cnt, cW1 + EDF * HH, cb1 + HH,
                                              agg, Xroot);
  node_update_k<<<NN / 16, 256, 0, stream>>>(hb, hpre0, sums0, gam, bet, 1,
                                             agg, deg, Xroot, cbias + MM,
                                             mW + MM * HH, mb + HH,
                                             hpre1, sums1);
  out_proj_k<<<NN / 4, 256, 0, stream>>>(hpre1, sums1, gam + HH, bet + HH,
                                         oW, ob, out);
}